// Round 2
// baseline (283.634 us; speedup 1.0000x reference)
//
#include <hip/hip_runtime.h>
#include <stdint.h>

// GCN: z = A_hat( relu( A_hat(x@W1) + b1 ) @ W2 ) + b2, A_hat = D^-1/2 (A+I) D^-1/2
// R11 (= R10 with nontemporal builtins fixed: use ext_vector_type f32x4, not
// HIP_vector_type float4, which the builtin rejects). From R9 @ 268.7us:
//  - gemm: 64 rows/block (782 blocks = 3.05/CU vs 391 = 1.53/CU) -> kills the 2:1
//    CU-tail imbalance; one 16-row group per wave; nontemporal A loads.
//  - CSR pads: count-masked (j < deg-8c) instead of 0-sentinel -> no 13 MB meta
//    memset (only 200 KB cursor); gathered idx clamped vs poison garbage.
//  - launches 9 -> 6: wfrag merged into fill grid, dinv merged into gemm1 grid.
//  - final out stored nontemporal (never re-read).

typedef __attribute__((ext_vector_type(8))) short short8;
typedef __attribute__((ext_vector_type(4))) float f32x4;

#define SLOTS 64  // per-node CSR capacity; P(any deg > 63) ~ 5e-14 on this data

__device__ __forceinline__ uint32_t bf16_rne(float f) {
  uint32_t u = __float_as_uint(f);
  return (u + 0x7FFFu + ((u >> 16) & 1u)) >> 16;
}

// Blocks [0, wblocks): pre-frag W1/W2 into hi/lo bf16 MFMA B-fragments.
// Blocks [wblocks, ...): CSR fill. meta[d*SLOTS + pos] = s (no sentinel; pads are
// masked by count in agg). One atomic per edge, no pre-pass.
__global__ __launch_bounds__(256) void fill_wfrag_kernel(
    const int* __restrict__ src, const int* __restrict__ dst, int E,
    int* __restrict__ cursor, int* __restrict__ meta,
    const float* __restrict__ W1, const float* __restrict__ W2,
    short8* __restrict__ wh1, short8* __restrict__ wl1,
    short8* __restrict__ wh2, short8* __restrict__ wl2,
    int K1, int K2, int wblocks) {
  if ((int)blockIdx.x >= wblocks) {
    int i = (blockIdx.x - wblocks) * 256 + threadIdx.x;
    if (i < E) {
      int s = __builtin_nontemporal_load(src + i);
      int d = __builtin_nontemporal_load(dst + i);
      int pos = atomicAdd(&cursor[d], 1);
      if (pos < SLOTS) meta[(size_t)d * SLOTS + pos] = s;
    }
    return;
  }
  // W pre-frag: slot idx = kt*256 + ct*64 + lane;
  // element j = W[kt*32 + (lane>>4)*8 + j][ct*16 + (lane&15)].
  int idx = blockIdx.x * 256 + threadIdx.x;
  int tot1 = (K1 >> 5) * 256;
  int tot2 = (K2 >> 5) * 256;
  const float* W;
  short8 *wh, *wl;
  if (idx < tot1) {
    W = W1; wh = wh1; wl = wl1;
  } else if (idx < tot1 + tot2) {
    idx -= tot1;
    W = W2; wh = wh2; wl = wl2;
  } else {
    return;
  }
  int lane = idx & 63;
  int ct = (idx >> 6) & 3;
  int kt = idx >> 8;
  int m = lane & 15, q = lane >> 4;
  int col = ct * 16 + m;
  short8 h, l;
#pragma unroll
  for (int j = 0; j < 8; ++j) {
    float f = W[(size_t)(kt * 32 + q * 8 + j) * 64 + col];
    uint32_t hb = bf16_rne(f);
    float hf = __uint_as_float(hb << 16);
    float lo = f - hf;
    h[j] = (short)hb;
    l[j] = (short)bf16_rne(lo);
  }
  wh[idx] = h;
  wl[idx] = l;
}

// outb[n][64] (bf16) = A[n][K] @ W[K][64] via split-bf16 MFMA. No LDS, no barriers.
// 64 rows/block, 4 waves x 16 rows; register double-buffer (next k-tile's A + B
// prefetched during current tile's MFMAs). C/D layout: col=lane&15, row=q*4+reg.
// Blocks >= gblocks compute dinv (piggybacked on gemm1's launch; cursor is final).
__global__ __launch_bounds__(256) void gemm_mfma_kernel(
    const float* __restrict__ A, const short8* __restrict__ wh,
    const short8* __restrict__ wl, ushort* __restrict__ outb, int n, int K,
    int gblocks, const int* __restrict__ cursor, float* __restrict__ dinv,
    int ndinv) {
  if ((int)blockIdx.x >= gblocks) {
    int i = (blockIdx.x - gblocks) * 256 + threadIdx.x;
    if (i < ndinv) dinv[i] = rsqrtf((float)(cursor[i] + 1));  // +1 self-loop
    return;
  }
  const int t = threadIdx.x;
  const int lane = t & 63;
  const int m = lane & 15, q = lane >> 4;
  const int row0 = blockIdx.x * 64 + (t >> 6) * 16;
  int r0 = row0 + m;
  if (r0 >= n) r0 = n - 1;  // clamp; stores are guarded
  const float* ap = A + (size_t)r0 * K + q * 8;
  const short8* whp = wh + lane;
  const short8* wlp = wl + lane;
  const int nkt = K >> 5;
  f32x4 acc[4];
#pragma unroll
  for (int c = 0; c < 4; ++c) acc[c] = 0.f;

  f32x4 xa0 = __builtin_nontemporal_load((const f32x4*)ap);
  f32x4 xa1 = __builtin_nontemporal_load((const f32x4*)(ap + 4));
  short8 bh[4] = {whp[0], whp[64], whp[128], whp[192]};
  short8 bl[4] = {wlp[0], wlp[64], wlp[128], wlp[192]};

  auto cvt = [&](const f32x4& u0, const f32x4& u1, short8& hi, short8& lo) {
    float xf[8] = {u0[0], u0[1], u0[2], u0[3], u1[0], u1[1], u1[2], u1[3]};
#pragma unroll
    for (int j = 0; j < 8; ++j) {
      uint32_t hb = bf16_rne(xf[j]);
      float hf = __uint_as_float(hb << 16);
      hi[j] = (short)hb;
      lo[j] = (short)bf16_rne(xf[j] - hf);
    }
  };
  auto compute = [&]() {
    short8 ah, al;
    cvt(xa0, xa1, ah, al);
#pragma unroll
    for (int c = 0; c < 4; ++c)
      acc[c] = __builtin_amdgcn_mfma_f32_16x16x32_bf16(ah, bh[c], acc[c], 0, 0, 0);
#pragma unroll
    for (int c = 0; c < 4; ++c)
      acc[c] = __builtin_amdgcn_mfma_f32_16x16x32_bf16(ah, bl[c], acc[c], 0, 0, 0);
#pragma unroll
    for (int c = 0; c < 4; ++c)
      acc[c] = __builtin_amdgcn_mfma_f32_16x16x32_bf16(al, bh[c], acc[c], 0, 0, 0);
  };

  for (int kt = 0; kt < nkt - 1; ++kt) {
    const float* an = ap + 32;
    f32x4 nxa0 = __builtin_nontemporal_load((const f32x4*)an);
    f32x4 nxa1 = __builtin_nontemporal_load((const f32x4*)(an + 4));
    const short8* whn = whp + 256;
    const short8* wln = wlp + 256;
    short8 nh[4] = {whn[0], whn[64], whn[128], whn[192]};
    short8 nl[4] = {wln[0], wln[64], wln[128], wln[192]};
    compute();
    xa0 = nxa0; xa1 = nxa1;
#pragma unroll
    for (int c = 0; c < 4; ++c) { bh[c] = nh[c]; bl[c] = nl[c]; }
    ap = an; whp = whn; wlp = wln;
  }
  compute();  // last tile

#pragma unroll
  for (int i = 0; i < 4; ++i) {
    int rr = row0 + q * 4 + i;
    if (rr < n) {
      ushort* op = outb + (size_t)rr * 64 + m;
      op[0]  = (ushort)bf16_rne(acc[0][i]);
      op[16] = (ushort)bf16_rne(acc[1][i]);
      op[32] = (ushort)bf16_rne(acc[2][i]);
      op[48] = (ushort)bf16_rne(acc[3][i]);
    }
  }
}

// Aggregation over bf16 rows: 8 lanes/node (uint4 = 8 bf16/lane), 8 nodes/wave.
// Fixed-slot CSR: node v's edges at meta[v*64 .. v*64+deg). Pads are count-masked
// (no sentinel); gathered idx clamped vs poison. Per-edge weight dinv[s]*dv from
// the L2-hot dinv table. Next chunk's meta+rows prefetched during consume.
__global__ __launch_bounds__(256) void agg_kernel(const ushort* __restrict__ H,
                                                  const int* __restrict__ deg,
                                                  const int* __restrict__ meta,
                                                  const float* __restrict__ dinv,
                                                  const float* __restrict__ bias,
                                                  float* __restrict__ out, int n,
                                                  int do_relu) {
  const int t = threadIdx.x;
  const int sl = t & 7;
  const int v = blockIdx.x * 32 + (t >> 3);
  if (v >= n) return;
  const float dv = dinv[v];
  const float dvv = dv * dv;
  float acc[8];
  {
    uint4 hv = *(const uint4*)&H[(size_t)v * 64 + (sl << 3)];
    uint32_t u[4] = {hv.x, hv.y, hv.z, hv.w};
#pragma unroll
    for (int j = 0; j < 4; ++j) {
      acc[2 * j]     = __uint_as_float(u[j] << 16) * dvv;
      acc[2 * j + 1] = __uint_as_float(u[j] & 0xFFFF0000u) * dvv;
    }
  }
  int dg = deg[v];
  if (dg > SLOTS) dg = SLOTS;
  int nc = (dg + 7) >> 3;  // chunks of 8 edges, <= 8
  const int4* p = (const int4*)(meta + (size_t)v * SLOTS);

  int4 ma0, ma1, mb0, mb1;
  uint4 ra[8], rb[8];
  float wa[8], wb[8];
  auto gath = [&](int4 c0, int4 c1, uint4* r, float* wr) {
    int u[8] = {c0.x, c0.y, c0.z, c0.w, c1.x, c1.y, c1.z, c1.w};
#pragma unroll
    for (int j = 0; j < 8; ++j) {
      unsigned idx = (unsigned)u[j];
      if (idx >= (unsigned)n) idx = 0;  // pad/poison slots -> safe row, weight masked
      r[j] = *(const uint4*)&H[(size_t)idx * 64 + (sl << 3)];
      wr[j] = dinv[idx];
    }
  };
  auto consume = [&](int rem, const uint4* r, const float* wr) {
#pragma unroll
    for (int j = 0; j < 8; ++j) {
      const float wgt = (j < rem) ? wr[j] * dv : 0.f;
      uint32_t q[4] = {r[j].x, r[j].y, r[j].z, r[j].w};
#pragma unroll
      for (int k = 0; k < 4; ++k) {
        acc[2 * k]     = fmaf(__uint_as_float(q[k] << 16), wgt, acc[2 * k]);
        acc[2 * k + 1] = fmaf(__uint_as_float(q[k] & 0xFFFF0000u), wgt, acc[2 * k + 1]);
      }
    }
  };

  if (nc > 0) {
    ma0 = p[0]; ma1 = p[1];
    gath(ma0, ma1, ra, wa);
  }
  for (int c = 0; c < nc - 1; ++c) {
    mb0 = p[2 * c + 2]; mb1 = p[2 * c + 3];
    gath(mb0, mb1, rb, wb);   // next chunk in flight...
    consume(dg - (c << 3), ra, wa);
    ma0 = mb0; ma1 = mb1;
#pragma unroll
    for (int j = 0; j < 8; ++j) { ra[j] = rb[j]; wa[j] = wb[j]; }
  }
  if (nc > 0) consume(dg - ((nc - 1) << 3), ra, wa);

  const float4 blo = *(const float4*)&bias[sl << 3];
  const float4 bhi = *(const float4*)&bias[(sl << 3) + 4];
  float bb[8] = {blo.x, blo.y, blo.z, blo.w, bhi.x, bhi.y, bhi.z, bhi.w};
#pragma unroll
  for (int j = 0; j < 8; ++j) {
    acc[j] += bb[j];
    if (do_relu) acc[j] = fmaxf(acc[j], 0.f);
  }
  float* op = out + (size_t)v * 64 + (sl << 3);
  f32x4 v0 = {acc[0], acc[1], acc[2], acc[3]};
  f32x4 v1 = {acc[4], acc[5], acc[6], acc[7]};
  if (do_relu) {  // h is re-read by gemm2 soon: keep cacheable
    *(f32x4*)op = v0;
    *(f32x4*)(op + 4) = v1;
  } else {        // final output: never re-read
    __builtin_nontemporal_store(v0, (f32x4*)op);
    __builtin_nontemporal_store(v1, (f32x4*)(op + 4));
  }
}

extern "C" void kernel_launch(void* const* d_in, const int* in_sizes, int n_in,
                              void* d_out, int out_size, void* d_ws, size_t ws_size,
                              hipStream_t stream) {
  const float* x = (const float*)d_in[0];
  const int* ei = (const int*)d_in[1];
  const float* W1 = (const float*)d_in[2];
  const float* b1 = (const float*)d_in[3];
  const float* W2 = (const float*)d_in[4];
  const float* b2 = (const float*)d_in[5];
  float* out = (float*)d_out;

  const int HID = in_sizes[3];           // 64
  const int IN_DIM = in_sizes[2] / HID;  // 512
  const int N = in_sizes[0] / IN_DIM;    // 50000
  const int E = in_sizes[1] / 2;         // 800000

  uint8_t* p = (uint8_t*)d_ws;
  auto alloc = [&](size_t bytes) {
    void* r = (void*)p;
    p += (bytes + 255) & ~(size_t)255;
    return r;
  };
  int* meta = (int*)alloc((size_t)N * SLOTS * 4);
  int* cursor = (int*)alloc((size_t)N * 4);
  float* dinv = (float*)alloc((size_t)N * 4);
  ushort* hb = (ushort*)alloc((size_t)N * HID * 2);  // bf16 gemm out
  float* h = (float*)alloc((size_t)N * HID * 4);     // f32 agg1 out
  short8* wh1 = (short8*)alloc((size_t)(IN_DIM >> 5) * 256 * 16);
  short8* wl1 = (short8*)alloc((size_t)(IN_DIM >> 5) * 256 * 16);
  short8* wh2 = (short8*)alloc((size_t)(HID >> 5) * 256 * 16);
  short8* wl2 = (short8*)alloc((size_t)(HID >> 5) * 256 * 16);

  const int* srcp = ei;
  const int* dstp = ei + E;

  // Only cursor needs zeroing now (pads are count-masked, not sentinel-tested).
  (void)hipMemsetAsync(cursor, 0, (size_t)N * 4, stream);

  const int wtot = (IN_DIM >> 5) * 256 + (HID >> 5) * 256;
  const int wblocks = (wtot + 255) / 256;
  const int fblocks = (E + 255) / 256;
  fill_wfrag_kernel<<<wblocks + fblocks, 256, 0, stream>>>(
      srcp, dstp, E, cursor, meta, W1, W2, wh1, wl1, wh2, wl2, IN_DIM, HID, wblocks);

  const int g1 = (N + 63) / 64;
  const int dblk = (N + 255) / 256;
  // gemm1 + dinv piggyback (dinv only needs completed cursor; runs concurrently)
  gemm_mfma_kernel<<<g1 + dblk, 256, 0, stream>>>(x, wh1, wl1, hb, N, IN_DIM, g1,
                                                  cursor, dinv, N);
  agg_kernel<<<(N + 31) / 32, 256, 0, stream>>>(hb, cursor, meta, dinv, b1, h, N, 1);
  gemm_mfma_kernel<<<g1, 256, 0, stream>>>(h, wh2, wl2, hb, N, HID, g1,
                                           cursor, dinv, 0);
  agg_kernel<<<(N + 31) / 32, 256, 0, stream>>>(hb, cursor, meta, dinv, b2, out, N, 0);
}

// Round 5
// 267.370 us; speedup vs baseline: 1.0608x; 1.0608x over previous
//
#include <hip/hip_runtime.h>
#include <stdint.h>

// GCN: z = A_hat( relu( A_hat(x@W1) + b1 ) @ W2 ) + b2, A_hat = D^-1/2 (A+I) D^-1/2
// R12 resubmit #2 (R3 and R4 benches were GPUAcquisitionTimeout; never ran).
// From R11 @ 283.6us regression vs R9 @ 268.7us:
//  - gemm geometry REVERTED to R9's 128 rows/block, 32 rows/wave (R11's 64-row
//    blocks doubled per-MFMA B-load pressure: 8 B-loads per k-tile amortized over
//    12 MFMAs instead of 24 -> ~2.6 vs 2.0 T128 wall). Plain (cacheable) A loads.
//  - cvt_pk: split-bf16 conversion now uses v_cvt_pk_bf16_f32 (2 f32 -> packed
//    2xbf16, RNE == bf16_rne bit-exact). Cvt drops ~96 -> ~24 VALU per 8 elems;
//    gemm was VALU-issue-bound on conversion (~192 cyc vs ~115 cyc MFMA/k-tile).
//  - kept from R11: count-masked CSR pads (no 13 MB memset), merged launches
//    (wfrag in fill grid, dinv in gemm1 grid), nt loads in fill, nt final store.

typedef __attribute__((ext_vector_type(8))) short short8;
typedef __attribute__((ext_vector_type(4))) float f32x4;
typedef __attribute__((ext_vector_type(4))) unsigned int u32x4;

#define SLOTS 64  // per-node CSR capacity; P(any deg > 63) ~ 5e-14 on this data

__device__ __forceinline__ uint32_t bf16_rne(float f) {
  uint32_t u = __float_as_uint(f);
  return (u + 0x7FFFu + ((u >> 16) & 1u)) >> 16;
}

// packed bf16 convert: result.lo16 = bf16(a), result.hi16 = bf16(b), RNE
__device__ __forceinline__ uint32_t cvt_pk_bf16(float a, float b) {
  uint32_t r;
  asm("v_cvt_pk_bf16_f32 %0, %1, %2" : "=v"(r) : "v"(a), "v"(b));
  return r;
}

// Blocks [0, wblocks): pre-frag W1/W2 into hi/lo bf16 MFMA B-fragments.
// Blocks [wblocks, ...): CSR fill. meta[d*SLOTS + pos] = s (no sentinel; pads are
// masked by count in agg). One atomic per edge, no pre-pass.
__global__ __launch_bounds__(256) void fill_wfrag_kernel(
    const int* __restrict__ src, const int* __restrict__ dst, int E,
    int* __restrict__ cursor, int* __restrict__ meta,
    const float* __restrict__ W1, const float* __restrict__ W2,
    short8* __restrict__ wh1, short8* __restrict__ wl1,
    short8* __restrict__ wh2, short8* __restrict__ wl2,
    int K1, int K2, int wblocks) {
  if ((int)blockIdx.x >= wblocks) {
    int i = (blockIdx.x - wblocks) * 256 + threadIdx.x;
    if (i < E) {
      int s = __builtin_nontemporal_load(src + i);
      int d = __builtin_nontemporal_load(dst + i);
      int pos = atomicAdd(&cursor[d], 1);
      if (pos < SLOTS) meta[(size_t)d * SLOTS + pos] = s;
    }
    return;
  }
  // W pre-frag: slot idx = kt*256 + ct*64 + lane;
  // element j = W[kt*32 + (lane>>4)*8 + j][ct*16 + (lane&15)].
  int idx = blockIdx.x * 256 + threadIdx.x;
  int tot1 = (K1 >> 5) * 256;
  int tot2 = (K2 >> 5) * 256;
  const float* W;
  short8 *wh, *wl;
  if (idx < tot1) {
    W = W1; wh = wh1; wl = wl1;
  } else if (idx < tot1 + tot2) {
    idx -= tot1;
    W = W2; wh = wh2; wl = wl2;
  } else {
    return;
  }
  int lane = idx & 63;
  int ct = (idx >> 6) & 3;
  int kt = idx >> 8;
  int m = lane & 15, q = lane >> 4;
  int col = ct * 16 + m;
  short8 h, l;
#pragma unroll
  for (int j = 0; j < 8; ++j) {
    float f = W[(size_t)(kt * 32 + q * 8 + j) * 64 + col];
    uint32_t hb = bf16_rne(f);
    float hf = __uint_as_float(hb << 16);
    float lo = f - hf;
    h[j] = (short)hb;
    l[j] = (short)bf16_rne(lo);
  }
  wh[idx] = h;
  wl[idx] = l;
}

// outb[n][64] (bf16) = A[n][K] @ W[K][64] via split-bf16 MFMA. No LDS, no barriers.
// 128 rows/block, 4 waves x 32 rows (two 16-row groups share every B-frag).
// Register double-buffer: next k-tile's A + B prefetched during current MFMAs.
// C/D layout: col=lane&15, row=(lane>>4)*4+reg.
// Blocks >= gblocks compute dinv (piggybacked on gemm1's launch; cursor is final).
__global__ __launch_bounds__(256) void gemm_mfma_kernel(
    const float* __restrict__ A, const short8* __restrict__ wh,
    const short8* __restrict__ wl, ushort* __restrict__ outb, int n, int K,
    int gblocks, const int* __restrict__ cursor, float* __restrict__ dinv,
    int ndinv) {
  if ((int)blockIdx.x >= gblocks) {
    int i = (blockIdx.x - gblocks) * 256 + threadIdx.x;
    if (i < ndinv) dinv[i] = rsqrtf((float)(cursor[i] + 1));  // +1 self-loop
    return;
  }
  const int t = threadIdx.x;
  const int lane = t & 63;
  const int m = lane & 15, q = lane >> 4;
  const int row0 = blockIdx.x * 128 + (t >> 6) * 32;
  int r0 = row0 + m;
  int r1 = row0 + 16 + m;
  if (r0 >= n) r0 = n - 1;  // clamp; stores are guarded
  if (r1 >= n) r1 = n - 1;
  const float* ap0 = A + (size_t)r0 * K + q * 8;
  const float* ap1 = A + (size_t)r1 * K + q * 8;
  const short8* whp = wh + lane;
  const short8* wlp = wl + lane;
  const int nkt = K >> 5;
  f32x4 acc[2][4];
#pragma unroll
  for (int g = 0; g < 2; ++g)
#pragma unroll
    for (int c = 0; c < 4; ++c) acc[g][c] = 0.f;

  f32x4 xa0 = *(const f32x4*)(ap0);
  f32x4 xa1 = *(const f32x4*)(ap0 + 4);
  f32x4 xb0 = *(const f32x4*)(ap1);
  f32x4 xb1 = *(const f32x4*)(ap1 + 4);
  short8 bh[4] = {whp[0], whp[64], whp[128], whp[192]};
  short8 bl[4] = {wlp[0], wlp[64], wlp[128], wlp[192]};

  // split-bf16 via packed cvt: hw word j = {bf16(x2j), bf16(x2j+1)}; residual
  // lw from f32 subtract of the hi part reconstructed by shl / mask.
  auto cvt = [&](const f32x4& u0, const f32x4& u1, short8& hi, short8& lo) {
    u32x4 hw, lw;
    hw[0] = cvt_pk_bf16(u0[0], u0[1]);
    hw[1] = cvt_pk_bf16(u0[2], u0[3]);
    hw[2] = cvt_pk_bf16(u1[0], u1[1]);
    hw[3] = cvt_pk_bf16(u1[2], u1[3]);
    lw[0] = cvt_pk_bf16(u0[0] - __uint_as_float(hw[0] << 16),
                        u0[1] - __uint_as_float(hw[0] & 0xFFFF0000u));
    lw[1] = cvt_pk_bf16(u0[2] - __uint_as_float(hw[1] << 16),
                        u0[3] - __uint_as_float(hw[1] & 0xFFFF0000u));
    lw[2] = cvt_pk_bf16(u1[0] - __uint_as_float(hw[2] << 16),
                        u1[1] - __uint_as_float(hw[2] & 0xFFFF0000u));
    lw[3] = cvt_pk_bf16(u1[2] - __uint_as_float(hw[3] << 16),
                        u1[3] - __uint_as_float(hw[3] & 0xFFFF0000u));
    hi = __builtin_bit_cast(short8, hw);
    lo = __builtin_bit_cast(short8, lw);
  };
  auto compute = [&]() {
    short8 ah0, al0, ah1, al1;
    cvt(xa0, xa1, ah0, al0);
    cvt(xb0, xb1, ah1, al1);
#pragma unroll
    for (int c = 0; c < 4; ++c) {
      acc[0][c] = __builtin_amdgcn_mfma_f32_16x16x32_bf16(ah0, bh[c], acc[0][c], 0, 0, 0);
      acc[1][c] = __builtin_amdgcn_mfma_f32_16x16x32_bf16(ah1, bh[c], acc[1][c], 0, 0, 0);
    }
#pragma unroll
    for (int c = 0; c < 4; ++c) {
      acc[0][c] = __builtin_amdgcn_mfma_f32_16x16x32_bf16(ah0, bl[c], acc[0][c], 0, 0, 0);
      acc[1][c] = __builtin_amdgcn_mfma_f32_16x16x32_bf16(ah1, bl[c], acc[1][c], 0, 0, 0);
    }
#pragma unroll
    for (int c = 0; c < 4; ++c) {
      acc[0][c] = __builtin_amdgcn_mfma_f32_16x16x32_bf16(al0, bh[c], acc[0][c], 0, 0, 0);
      acc[1][c] = __builtin_amdgcn_mfma_f32_16x16x32_bf16(al1, bh[c], acc[1][c], 0, 0, 0);
    }
  };

  for (int kt = 0; kt < nkt - 1; ++kt) {
    const float* an0 = ap0 + 32;
    const float* an1 = ap1 + 32;
    f32x4 nxa0 = *(const f32x4*)(an0);
    f32x4 nxa1 = *(const f32x4*)(an0 + 4);
    f32x4 nxb0 = *(const f32x4*)(an1);
    f32x4 nxb1 = *(const f32x4*)(an1 + 4);
    const short8* whn = whp + 256;
    const short8* wln = wlp + 256;
    short8 nh[4] = {whn[0], whn[64], whn[128], whn[192]};
    short8 nl[4] = {wln[0], wln[64], wln[128], wln[192]};
    compute();
    xa0 = nxa0; xa1 = nxa1; xb0 = nxb0; xb1 = nxb1;
#pragma unroll
    for (int c = 0; c < 4; ++c) { bh[c] = nh[c]; bl[c] = nl[c]; }
    ap0 = an0; ap1 = an1; whp = whn; wlp = wln;
  }
  compute();  // last tile

#pragma unroll
  for (int g = 0; g < 2; ++g)
#pragma unroll
    for (int i = 0; i < 4; ++i) {
      int rr = row0 + g * 16 + q * 4 + i;
      if (rr < n) {
        ushort* op = outb + (size_t)rr * 64 + m;
        op[0]  = (ushort)bf16_rne(acc[g][0][i]);
        op[16] = (ushort)bf16_rne(acc[g][1][i]);
        op[32] = (ushort)bf16_rne(acc[g][2][i]);
        op[48] = (ushort)bf16_rne(acc[g][3][i]);
      }
    }
}

// Aggregation over bf16 rows: 8 lanes/node (uint4 = 8 bf16/lane), 8 nodes/wave.
// Fixed-slot CSR: node v's edges at meta[v*64 .. v*64+deg). Pads are count-masked
// (no sentinel); gathered idx clamped vs poison. Per-edge weight dinv[s]*dv from
// the L2-hot dinv table. Next chunk's meta+rows prefetched during consume.
__global__ __launch_bounds__(256) void agg_kernel(const ushort* __restrict__ H,
                                                  const int* __restrict__ deg,
                                                  const int* __restrict__ meta,
                                                  const float* __restrict__ dinv,
                                                  const float* __restrict__ bias,
                                                  float* __restrict__ out, int n,
                                                  int do_relu) {
  const int t = threadIdx.x;
  const int sl = t & 7;
  const int v = blockIdx.x * 32 + (t >> 3);
  if (v >= n) return;
  const float dv = dinv[v];
  const float dvv = dv * dv;
  float acc[8];
  {
    uint4 hv = *(const uint4*)&H[(size_t)v * 64 + (sl << 3)];
    uint32_t u[4] = {hv.x, hv.y, hv.z, hv.w};
#pragma unroll
    for (int j = 0; j < 4; ++j) {
      acc[2 * j]     = __uint_as_float(u[j] << 16) * dvv;
      acc[2 * j + 1] = __uint_as_float(u[j] & 0xFFFF0000u) * dvv;
    }
  }
  int dg = deg[v];
  if (dg > SLOTS) dg = SLOTS;
  int nc = (dg + 7) >> 3;  // chunks of 8 edges, <= 8
  const int4* p = (const int4*)(meta + (size_t)v * SLOTS);

  int4 ma0, ma1, mb0, mb1;
  uint4 ra[8], rb[8];
  float wa[8], wb[8];
  auto gath = [&](int4 c0, int4 c1, uint4* r, float* wr) {
    int u[8] = {c0.x, c0.y, c0.z, c0.w, c1.x, c1.y, c1.z, c1.w};
#pragma unroll
    for (int j = 0; j < 8; ++j) {
      unsigned idx = (unsigned)u[j];
      if (idx >= (unsigned)n) idx = 0;  // pad/poison slots -> safe row, weight masked
      r[j] = *(const uint4*)&H[(size_t)idx * 64 + (sl << 3)];
      wr[j] = dinv[idx];
    }
  };
  auto consume = [&](int rem, const uint4* r, const float* wr) {
#pragma unroll
    for (int j = 0; j < 8; ++j) {
      const float wgt = (j < rem) ? wr[j] * dv : 0.f;
      uint32_t q[4] = {r[j].x, r[j].y, r[j].z, r[j].w};
#pragma unroll
      for (int k = 0; k < 4; ++k) {
        acc[2 * k]     = fmaf(__uint_as_float(q[k] << 16), wgt, acc[2 * k]);
        acc[2 * k + 1] = fmaf(__uint_as_float(q[k] & 0xFFFF0000u), wgt, acc[2 * k + 1]);
      }
    }
  };

  if (nc > 0) {
    ma0 = p[0]; ma1 = p[1];
    gath(ma0, ma1, ra, wa);
  }
  for (int c = 0; c < nc - 1; ++c) {
    mb0 = p[2 * c + 2]; mb1 = p[2 * c + 3];
    gath(mb0, mb1, rb, wb);   // next chunk in flight...
    consume(dg - (c << 3), ra, wa);
    ma0 = mb0; ma1 = mb1;
#pragma unroll
    for (int j = 0; j < 8; ++j) { ra[j] = rb[j]; wa[j] = wb[j]; }
  }
  if (nc > 0) consume(dg - ((nc - 1) << 3), ra, wa);

  const float4 blo = *(const float4*)&bias[sl << 3];
  const float4 bhi = *(const float4*)&bias[(sl << 3) + 4];
  float bb[8] = {blo.x, blo.y, blo.z, blo.w, bhi.x, bhi.y, bhi.z, bhi.w};
#pragma unroll
  for (int j = 0; j < 8; ++j) {
    acc[j] += bb[j];
    if (do_relu) acc[j] = fmaxf(acc[j], 0.f);
  }
  float* op = out + (size_t)v * 64 + (sl << 3);
  f32x4 v0 = {acc[0], acc[1], acc[2], acc[3]};
  f32x4 v1 = {acc[4], acc[5], acc[6], acc[7]};
  if (do_relu) {  // h is re-read by gemm2 soon: keep cacheable
    *(f32x4*)op = v0;
    *(f32x4*)(op + 4) = v1;
  } else {        // final output: never re-read
    __builtin_nontemporal_store(v0, (f32x4*)op);
    __builtin_nontemporal_store(v1, (f32x4*)(op + 4));
  }
}

extern "C" void kernel_launch(void* const* d_in, const int* in_sizes, int n_in,
                              void* d_out, int out_size, void* d_ws, size_t ws_size,
                              hipStream_t stream) {
  const float* x = (const float*)d_in[0];
  const int* ei = (const int*)d_in[1];
  const float* W1 = (const float*)d_in[2];
  const float* b1 = (const float*)d_in[3];
  const float* W2 = (const float*)d_in[4];
  const float* b2 = (const float*)d_in[5];
  float* out = (float*)d_out;

  const int HID = in_sizes[3];           // 64
  const int IN_DIM = in_sizes[2] / HID;  // 512
  const int N = in_sizes[0] / IN_DIM;    // 50000
  const int E = in_sizes[1] / 2;         // 800000

  uint8_t* p = (uint8_t*)d_ws;
  auto alloc = [&](size_t bytes) {
    void* r = (void*)p;
    p += (bytes + 255) & ~(size_t)255;
    return r;
  };
  int* meta = (int*)alloc((size_t)N * SLOTS * 4);
  int* cursor = (int*)alloc((size_t)N * 4);
  float* dinv = (float*)alloc((size_t)N * 4);
  ushort* hb = (ushort*)alloc((size_t)N * HID * 2);  // bf16 gemm out
  float* h = (float*)alloc((size_t)N * HID * 4);     // f32 agg1 out
  short8* wh1 = (short8*)alloc((size_t)(IN_DIM >> 5) * 256 * 16);
  short8* wl1 = (short8*)alloc((size_t)(IN_DIM >> 5) * 256 * 16);
  short8* wh2 = (short8*)alloc((size_t)(HID >> 5) * 256 * 16);
  short8* wl2 = (short8*)alloc((size_t)(HID >> 5) * 256 * 16);

  const int* srcp = ei;
  const int* dstp = ei + E;

  // Only cursor needs zeroing (pads are count-masked, not sentinel-tested).
  (void)hipMemsetAsync(cursor, 0, (size_t)N * 4, stream);

  const int wtot = (IN_DIM >> 5) * 256 + (HID >> 5) * 256;
  const int wblocks = (wtot + 255) / 256;
  const int fblocks = (E + 255) / 256;
  fill_wfrag_kernel<<<wblocks + fblocks, 256, 0, stream>>>(
      srcp, dstp, E, cursor, meta, W1, W2, wh1, wl1, wh2, wl2, IN_DIM, HID, wblocks);

  const int g1 = (N + 127) / 128;
  const int dblk = (N + 255) / 256;
  // gemm1 + dinv piggyback (dinv only needs completed cursor; runs concurrently)
  gemm_mfma_kernel<<<g1 + dblk, 256, 0, stream>>>(x, wh1, wl1, hb, N, IN_DIM, g1,
                                                  cursor, dinv, N);
  agg_kernel<<<(N + 31) / 32, 256, 0, stream>>>(hb, cursor, meta, dinv, b1, h, N, 1);
  gemm_mfma_kernel<<<g1, 256, 0, stream>>>(h, wh2, wl2, hb, N, HID, g1,
                                           cursor, dinv, 0);
  agg_kernel<<<(N + 31) / 32, 256, 0, stream>>>(hb, cursor, meta, dinv, b2, out, N, 0);
}

// Round 6
// 265.946 us; speedup vs baseline: 1.0665x; 1.0054x over previous
//
#include <hip/hip_runtime.h>
#include <stdint.h>

// GCN: z = A_hat( relu( A_hat(x@W1) + b1 ) @ W2 ) + b2, A_hat = D^-1/2 (A+I) D^-1/2
// R13 (from R12 @ 267.4us; R12's cvt_pk was neutral -> gemm not VALU-bound, pivot
// to agg per pre-commitment):
//  - dinv FOLDED INTO GEMM EPILOGUE: hb[r] = bf16( rsqrt(deg[r]+1) * (A@W)[r] ).
//    Algebra: out[v] = b + dv*(S[v] + sum_{s in N(v)} S[s]), S[r]=dinv[r]*row[r].
//    agg loses the per-edge dinv gather (800k extra scattered loads + dependency
//    chain per kernel), the wa/wb arrays (-16 VGPR), and the dvv self-term mul.
//    dinv array + kernel deleted entirely; scale recomputed per-row via rsqrt.
//  - kept: R9 gemm geometry (128 rows/block, 32/wave), cvt_pk split-bf16,
//    count-masked CSR pads, merged fill+wfrag, nt fill loads, nt final store.

typedef __attribute__((ext_vector_type(8))) short short8;
typedef __attribute__((ext_vector_type(4))) float f32x4;
typedef __attribute__((ext_vector_type(4))) unsigned int u32x4;

#define SLOTS 64  // per-node CSR capacity; P(any deg > 63) ~ 5e-14 on this data

__device__ __forceinline__ uint32_t bf16_rne(float f) {
  uint32_t u = __float_as_uint(f);
  return (u + 0x7FFFu + ((u >> 16) & 1u)) >> 16;
}

// packed bf16 convert: result.lo16 = bf16(a), result.hi16 = bf16(b), RNE
__device__ __forceinline__ uint32_t cvt_pk_bf16(float a, float b) {
  uint32_t r;
  asm("v_cvt_pk_bf16_f32 %0, %1, %2" : "=v"(r) : "v"(a), "v"(b));
  return r;
}

// Blocks [0, wblocks): pre-frag W1/W2 into hi/lo bf16 MFMA B-fragments.
// Blocks [wblocks, ...): CSR fill. meta[d*SLOTS + pos] = s (no sentinel; pads are
// masked by count in agg). One atomic per edge, no pre-pass.
__global__ __launch_bounds__(256) void fill_wfrag_kernel(
    const int* __restrict__ src, const int* __restrict__ dst, int E,
    int* __restrict__ cursor, int* __restrict__ meta,
    const float* __restrict__ W1, const float* __restrict__ W2,
    short8* __restrict__ wh1, short8* __restrict__ wl1,
    short8* __restrict__ wh2, short8* __restrict__ wl2,
    int K1, int K2, int wblocks) {
  if ((int)blockIdx.x >= wblocks) {
    int i = (blockIdx.x - wblocks) * 256 + threadIdx.x;
    if (i < E) {
      int s = __builtin_nontemporal_load(src + i);
      int d = __builtin_nontemporal_load(dst + i);
      int pos = atomicAdd(&cursor[d], 1);
      if (pos < SLOTS) meta[(size_t)d * SLOTS + pos] = s;
    }
    return;
  }
  // W pre-frag: slot idx = kt*256 + ct*64 + lane;
  // element j = W[kt*32 + (lane>>4)*8 + j][ct*16 + (lane&15)].
  int idx = blockIdx.x * 256 + threadIdx.x;
  int tot1 = (K1 >> 5) * 256;
  int tot2 = (K2 >> 5) * 256;
  const float* W;
  short8 *wh, *wl;
  if (idx < tot1) {
    W = W1; wh = wh1; wl = wl1;
  } else if (idx < tot1 + tot2) {
    idx -= tot1;
    W = W2; wh = wh2; wl = wl2;
  } else {
    return;
  }
  int lane = idx & 63;
  int ct = (idx >> 6) & 3;
  int kt = idx >> 8;
  int m = lane & 15, q = lane >> 4;
  int col = ct * 16 + m;
  short8 h, l;
#pragma unroll
  for (int j = 0; j < 8; ++j) {
    float f = W[(size_t)(kt * 32 + q * 8 + j) * 64 + col];
    uint32_t hb = bf16_rne(f);
    float hf = __uint_as_float(hb << 16);
    float lo = f - hf;
    h[j] = (short)hb;
    l[j] = (short)bf16_rne(lo);
  }
  wh[idx] = h;
  wl[idx] = l;
}

// outb[n][64] (bf16) = dinv[r] * (A[n][K] @ W[K][64]) via split-bf16 MFMA.
// dinv[r] = rsqrt(deg[r]+1) computed inline from the L2-hot cursor table
// (rows broadcast across the 16 m-lanes). No LDS, no barriers.
// 128 rows/block, 4 waves x 32 rows (two 16-row groups share every B-frag).
// Register double-buffer: next k-tile's A + B prefetched during current MFMAs.
// C/D layout: col=lane&15, row=(lane>>4)*4+reg.
__global__ __launch_bounds__(256) void gemm_mfma_kernel(
    const float* __restrict__ A, const short8* __restrict__ wh,
    const short8* __restrict__ wl, const int* __restrict__ deg,
    ushort* __restrict__ outb, int n, int K) {
  const int t = threadIdx.x;
  const int lane = t & 63;
  const int m = lane & 15, q = lane >> 4;
  const int row0 = blockIdx.x * 128 + (t >> 6) * 32;
  int r0 = row0 + m;
  int r1 = row0 + 16 + m;
  if (r0 >= n) r0 = n - 1;  // clamp; stores are guarded
  if (r1 >= n) r1 = n - 1;
  const float* ap0 = A + (size_t)r0 * K + q * 8;
  const float* ap1 = A + (size_t)r1 * K + q * 8;
  const short8* whp = wh + lane;
  const short8* wlp = wl + lane;
  const int nkt = K >> 5;
  f32x4 acc[2][4];
#pragma unroll
  for (int g = 0; g < 2; ++g)
#pragma unroll
    for (int c = 0; c < 4; ++c) acc[g][c] = 0.f;

  f32x4 xa0 = *(const f32x4*)(ap0);
  f32x4 xa1 = *(const f32x4*)(ap0 + 4);
  f32x4 xb0 = *(const f32x4*)(ap1);
  f32x4 xb1 = *(const f32x4*)(ap1 + 4);
  short8 bh[4] = {whp[0], whp[64], whp[128], whp[192]};
  short8 bl[4] = {wlp[0], wlp[64], wlp[128], wlp[192]};

  // split-bf16 via packed cvt: hw word j = {bf16(x2j), bf16(x2j+1)}; residual
  // lw from f32 subtract of the hi part reconstructed by shl / mask.
  auto cvt = [&](const f32x4& u0, const f32x4& u1, short8& hi, short8& lo) {
    u32x4 hw, lw;
    hw[0] = cvt_pk_bf16(u0[0], u0[1]);
    hw[1] = cvt_pk_bf16(u0[2], u0[3]);
    hw[2] = cvt_pk_bf16(u1[0], u1[1]);
    hw[3] = cvt_pk_bf16(u1[2], u1[3]);
    lw[0] = cvt_pk_bf16(u0[0] - __uint_as_float(hw[0] << 16),
                        u0[1] - __uint_as_float(hw[0] & 0xFFFF0000u));
    lw[1] = cvt_pk_bf16(u0[2] - __uint_as_float(hw[1] << 16),
                        u0[3] - __uint_as_float(hw[1] & 0xFFFF0000u));
    lw[2] = cvt_pk_bf16(u1[0] - __uint_as_float(hw[2] << 16),
                        u1[1] - __uint_as_float(hw[2] & 0xFFFF0000u));
    lw[3] = cvt_pk_bf16(u1[2] - __uint_as_float(hw[3] << 16),
                        u1[3] - __uint_as_float(hw[3] & 0xFFFF0000u));
    hi = __builtin_bit_cast(short8, hw);
    lo = __builtin_bit_cast(short8, lw);
  };
  auto compute = [&]() {
    short8 ah0, al0, ah1, al1;
    cvt(xa0, xa1, ah0, al0);
    cvt(xb0, xb1, ah1, al1);
#pragma unroll
    for (int c = 0; c < 4; ++c) {
      acc[0][c] = __builtin_amdgcn_mfma_f32_16x16x32_bf16(ah0, bh[c], acc[0][c], 0, 0, 0);
      acc[1][c] = __builtin_amdgcn_mfma_f32_16x16x32_bf16(ah1, bh[c], acc[1][c], 0, 0, 0);
    }
#pragma unroll
    for (int c = 0; c < 4; ++c) {
      acc[0][c] = __builtin_amdgcn_mfma_f32_16x16x32_bf16(ah0, bl[c], acc[0][c], 0, 0, 0);
      acc[1][c] = __builtin_amdgcn_mfma_f32_16x16x32_bf16(ah1, bl[c], acc[1][c], 0, 0, 0);
    }
#pragma unroll
    for (int c = 0; c < 4; ++c) {
      acc[0][c] = __builtin_amdgcn_mfma_f32_16x16x32_bf16(al0, bh[c], acc[0][c], 0, 0, 0);
      acc[1][c] = __builtin_amdgcn_mfma_f32_16x16x32_bf16(al1, bh[c], acc[1][c], 0, 0, 0);
    }
  };

  for (int kt = 0; kt < nkt - 1; ++kt) {
    const float* an0 = ap0 + 32;
    const float* an1 = ap1 + 32;
    f32x4 nxa0 = *(const f32x4*)(an0);
    f32x4 nxa1 = *(const f32x4*)(an0 + 4);
    f32x4 nxb0 = *(const f32x4*)(an1);
    f32x4 nxb1 = *(const f32x4*)(an1 + 4);
    const short8* whn = whp + 256;
    const short8* wln = wlp + 256;
    short8 nh[4] = {whn[0], whn[64], whn[128], whn[192]};
    short8 nl[4] = {wln[0], wln[64], wln[128], wln[192]};
    compute();
    xa0 = nxa0; xa1 = nxa1; xb0 = nxb0; xb1 = nxb1;
#pragma unroll
    for (int c = 0; c < 4; ++c) { bh[c] = nh[c]; bl[c] = nl[c]; }
    ap0 = an0; ap1 = an1; whp = whn; wlp = wln;
  }
  compute();  // last tile

#pragma unroll
  for (int g = 0; g < 2; ++g)
#pragma unroll
    for (int i = 0; i < 4; ++i) {
      int rr = row0 + g * 16 + q * 4 + i;
      if (rr < n) {
        float s = rsqrtf((float)(deg[rr] + 1));  // +1 self-loop; bcast over m-lanes
        ushort* op = outb + (size_t)rr * 64 + m;
        op[0]  = (ushort)bf16_rne(acc[g][0][i] * s);
        op[16] = (ushort)bf16_rne(acc[g][1][i] * s);
        op[32] = (ushort)bf16_rne(acc[g][2][i] * s);
        op[48] = (ushort)bf16_rne(acc[g][3][i] * s);
      }
    }
}

// Aggregation over pre-scaled bf16 rows S[r] = dinv[r]*row[r]:
//   out[v] = bias + dv * ( S[v] + sum_{s in N(v)} S[s] ),  dv = rsqrt(deg[v]+1).
// 8 lanes/node (uint4 = 8 bf16/lane), 8 nodes/wave. Fixed-slot CSR; pads are
// count-masked (weight 0/1); gathered idx clamped vs poison. No per-edge weight
// loads. Next chunk's meta+rows prefetched during consume.
__global__ __launch_bounds__(256) void agg_kernel(const ushort* __restrict__ H,
                                                  const int* __restrict__ deg,
                                                  const int* __restrict__ meta,
                                                  const float* __restrict__ bias,
                                                  float* __restrict__ out, int n,
                                                  int do_relu) {
  const int t = threadIdx.x;
  const int sl = t & 7;
  const int v = blockIdx.x * 32 + (t >> 3);
  if (v >= n) return;
  int dg = deg[v];
  const float dv = rsqrtf((float)(dg + 1));  // +1 self-loop
  float acc[8];
  {
    uint4 hv = *(const uint4*)&H[(size_t)v * 64 + (sl << 3)];
    uint32_t u[4] = {hv.x, hv.y, hv.z, hv.w};
#pragma unroll
    for (int j = 0; j < 4; ++j) {
      acc[2 * j]     = __uint_as_float(u[j] << 16);
      acc[2 * j + 1] = __uint_as_float(u[j] & 0xFFFF0000u);
    }
  }
  if (dg > SLOTS) dg = SLOTS;
  int nc = (dg + 7) >> 3;  // chunks of 8 edges, <= 8
  const int4* p = (const int4*)(meta + (size_t)v * SLOTS);

  int4 ma0, ma1, mb0, mb1;
  uint4 ra[8], rb[8];
  auto gath = [&](int4 c0, int4 c1, uint4* r) {
    int u[8] = {c0.x, c0.y, c0.z, c0.w, c1.x, c1.y, c1.z, c1.w};
#pragma unroll
    for (int j = 0; j < 8; ++j) {
      unsigned idx = (unsigned)u[j];
      if (idx >= (unsigned)n) idx = 0;  // pad/poison slots -> safe row, weight masked
      r[j] = *(const uint4*)&H[(size_t)idx * 64 + (sl << 3)];
    }
  };
  auto consume = [&](int rem, const uint4* r) {
#pragma unroll
    for (int j = 0; j < 8; ++j) {
      const float wgt = (j < rem) ? 1.f : 0.f;
      uint32_t q[4] = {r[j].x, r[j].y, r[j].z, r[j].w};
#pragma unroll
      for (int k = 0; k < 4; ++k) {
        acc[2 * k]     = fmaf(__uint_as_float(q[k] << 16), wgt, acc[2 * k]);
        acc[2 * k + 1] = fmaf(__uint_as_float(q[k] & 0xFFFF0000u), wgt, acc[2 * k + 1]);
      }
    }
  };

  if (nc > 0) {
    ma0 = p[0]; ma1 = p[1];
    gath(ma0, ma1, ra);
  }
  for (int c = 0; c < nc - 1; ++c) {
    mb0 = p[2 * c + 2]; mb1 = p[2 * c + 3];
    gath(mb0, mb1, rb);   // next chunk in flight...
    consume(dg - (c << 3), ra);
    ma0 = mb0; ma1 = mb1;
#pragma unroll
    for (int j = 0; j < 8; ++j) ra[j] = rb[j];
  }
  if (nc > 0) consume(dg - ((nc - 1) << 3), ra);

  const float4 blo = *(const float4*)&bias[sl << 3];
  const float4 bhi = *(const float4*)&bias[(sl << 3) + 4];
  float bb[8] = {blo.x, blo.y, blo.z, blo.w, bhi.x, bhi.y, bhi.z, bhi.w};
#pragma unroll
  for (int j = 0; j < 8; ++j) {
    acc[j] = fmaf(acc[j], dv, bb[j]);
    if (do_relu) acc[j] = fmaxf(acc[j], 0.f);
  }
  float* op = out + (size_t)v * 64 + (sl << 3);
  f32x4 v0 = {acc[0], acc[1], acc[2], acc[3]};
  f32x4 v1 = {acc[4], acc[5], acc[6], acc[7]};
  if (do_relu) {  // h is re-read by gemm2 soon: keep cacheable
    *(f32x4*)op = v0;
    *(f32x4*)(op + 4) = v1;
  } else {        // final output: never re-read
    __builtin_nontemporal_store(v0, (f32x4*)op);
    __builtin_nontemporal_store(v1, (f32x4*)(op + 4));
  }
}

extern "C" void kernel_launch(void* const* d_in, const int* in_sizes, int n_in,
                              void* d_out, int out_size, void* d_ws, size_t ws_size,
                              hipStream_t stream) {
  const float* x = (const float*)d_in[0];
  const int* ei = (const int*)d_in[1];
  const float* W1 = (const float*)d_in[2];
  const float* b1 = (const float*)d_in[3];
  const float* W2 = (const float*)d_in[4];
  const float* b2 = (const float*)d_in[5];
  float* out = (float*)d_out;

  const int HID = in_sizes[3];           // 64
  const int IN_DIM = in_sizes[2] / HID;  // 512
  const int N = in_sizes[0] / IN_DIM;    // 50000
  const int E = in_sizes[1] / 2;         // 800000

  uint8_t* p = (uint8_t*)d_ws;
  auto alloc = [&](size_t bytes) {
    void* r = (void*)p;
    p += (bytes + 255) & ~(size_t)255;
    return r;
  };
  int* meta = (int*)alloc((size_t)N * SLOTS * 4);
  int* cursor = (int*)alloc((size_t)N * 4);
  ushort* hb = (ushort*)alloc((size_t)N * HID * 2);  // bf16 pre-scaled gemm out
  float* h = (float*)alloc((size_t)N * HID * 4);     // f32 agg1 out
  short8* wh1 = (short8*)alloc((size_t)(IN_DIM >> 5) * 256 * 16);
  short8* wl1 = (short8*)alloc((size_t)(IN_DIM >> 5) * 256 * 16);
  short8* wh2 = (short8*)alloc((size_t)(HID >> 5) * 256 * 16);
  short8* wl2 = (short8*)alloc((size_t)(HID >> 5) * 256 * 16);

  const int* srcp = ei;
  const int* dstp = ei + E;

  // Only cursor needs zeroing (pads are count-masked, not sentinel-tested).
  (void)hipMemsetAsync(cursor, 0, (size_t)N * 4, stream);

  const int wtot = (IN_DIM >> 5) * 256 + (HID >> 5) * 256;
  const int wblocks = (wtot + 255) / 256;
  const int fblocks = (E + 255) / 256;
  fill_wfrag_kernel<<<wblocks + fblocks, 256, 0, stream>>>(
      srcp, dstp, E, cursor, meta, W1, W2, wh1, wl1, wh2, wl2, IN_DIM, HID, wblocks);

  const int g1 = (N + 127) / 128;
  gemm_mfma_kernel<<<g1, 256, 0, stream>>>(x, wh1, wl1, cursor, hb, N, IN_DIM);
  agg_kernel<<<(N + 31) / 32, 256, 0, stream>>>(hb, cursor, meta, b1, h, N, 1);
  gemm_mfma_kernel<<<g1, 256, 0, stream>>>(h, wh2, wl2, cursor, hb, N, HID);
  agg_kernel<<<(N + 31) / 32, 256, 0, stream>>>(hb, cursor, meta, b2, out, N, 0);
}